// Round 10
// baseline (1411.030 us; speedup 1.0000x reference)
//
#include <hip/hip_runtime.h>

// ---------------------------------------------------------------------------
// WindowAttention fused pipeline for MI355X (gfx950)
//   B=2048 windows, N=128 tokens, C=256, H=8 heads, hd=32
// Round-10: split-pipe Phase A + 3 blocks/CU.
//   vs r9: (1) W u-units 0..2 staged in LDS (24KB, fragment order); u-units
//   3..5 read DIRECTLY from global with parity-register prefetch -- Phase-A
//   LDS reads halve (the LDS data pipe was ~54% of cycles).
//   (2) LDS 53.8KB -> 3 blocks/CU = 6 waves/SIMD (launch_bounds (512,6)).
//   (3) exp2 folding: Q-scale *= log2e, bias *= log2e -> exp2f in softmax.
// xcat (bf16) lives in d_out; proj GEMM runs in-place (proven path).
// ---------------------------------------------------------------------------

typedef __attribute__((ext_vector_type(8))) short     short8;
typedef __attribute__((ext_vector_type(8))) __bf16    bf16x8;
typedef __attribute__((ext_vector_type(4))) float     f32x4;

#define LOG2E 1.4426950408889634f

__device__ __forceinline__ unsigned short f2bf(float f) {
  return __builtin_bit_cast(unsigned short, (__bf16)f);   // native cvt, RTNE
}

__device__ __forceinline__ void gload_lds16(const void* g, void* l) {
  __builtin_amdgcn_global_load_lds((const __attribute__((address_space(1))) void*)g,
                                   (__attribute__((address_space(3))) void*)l, 16, 0, 0);
}

// ---------------- precompute kernels ----------------

__global__ void pos_kernel(float* __restrict__ pos_t) {
  int e = blockIdx.x * 256 + threadIdx.x;          // 32768 = 128*256
  int t = e >> 8, c = e & 255;
  int p = t & 63;                                   // tiled (1,2,1)
  const float norm = 6.28318530717958647692f / 8.000001f;  // scale/(8+1e-6)
  float yn = (float)((p >> 3) + 1) * norm;
  float xn = (float)((p & 7) + 1) * norm;
  int cc = c & 127;
  int m  = cc >> 1;
  float v = ((c < 128) ? yn : xn) * __expf(-(float)m * 0.14391156831f);
  pos_t[e] = (cc & 1) ? cosf(v) : sinf(v);
}

__global__ void posw_kernel(const float* __restrict__ pos_t,
                            const float* __restrict__ Wm,
                            float* __restrict__ posW) {
  int e = blockIdx.x * 256 + threadIdx.x;          // 98304 = 128*768
  int t = e / 768, c = e - t * 768;
  const float4* pr = (const float4*)(pos_t + t * 256);
  const float4* wr = (const float4*)(Wm + (size_t)c * 256);
  float acc = 0.f;
  #pragma unroll 8
  for (int k = 0; k < 64; ++k) {
    float4 p = pr[k], w = wr[k];
    acc += p.x * w.x + p.y * w.y + p.z * w.z + p.w * w.w;
  }
  if (c < 256) acc *= 0.17677669529663688f * LOG2E;  // fold attn scale + log2e into Q
  posW[e] = acc;
}

__global__ void bias_kernel(const float* __restrict__ rpb, float* __restrict__ bias_t) {
  int e = blockIdx.x * 256 + threadIdx.x;          // 131072 = 8*128*128
  int h = e >> 14, i = (e >> 7) & 127, j = e & 127;
  int di = i >> 6, hi = (i >> 3) & 7, wi = i & 7;
  int dj = j >> 6, hj = (j >> 3) & 7, wj = j & 7;
  int idx = (di - dj + 1) * 225 + (hi - hj + 7) * 15 + (wi - wj + 7);
  bias_t[e] = rpb[idx * 8 + h] * LOG2E;            // folded for exp2
}

__global__ void wconv_kernel(const float* __restrict__ Ws, const float* __restrict__ Wm,
                             const float* __restrict__ Wp,
                             unsigned short* __restrict__ Wsb,
                             unsigned short* __restrict__ Wmb,
                             unsigned short* __restrict__ Wpb) {
  int e = blockIdx.x * 256 + threadIdx.x;          // 524288
  const float qs = 0.17677669529663688f * LOG2E;   // 32^-0.5 * log2e into Q rows
  if (e < 196608) {
    float v = Ws[e]; if (e < 65536) v *= qs;       // rows 0..255 = Q
    Wsb[e] = f2bf(v);
  } else if (e < 393216) {
    int i = e - 196608;
    float v = Wm[i]; if (i < 65536) v *= qs;
    Wmb[i] = f2bf(v);
  } else {
    Wpb[e - 393216] = f2bf(Wp[e - 393216]);
  }
}

__global__ void xconv_kernel(const float* __restrict__ x, unsigned short* __restrict__ xb16) {
  // x has 67,108,864 f32 elements (2048*128*256); 8 per thread, grid-stride.
  for (size_t i8 = ((size_t)blockIdx.x * 256 + threadIdx.x) * 8; i8 < 67108864ull;
       i8 += (size_t)gridDim.x * 256 * 8) {
    float4 a = *(const float4*)(x + i8);
    float4 d = *(const float4*)(x + i8 + 4);
    short8 o;
    o[0] = (short)f2bf(a.x); o[1] = (short)f2bf(a.y);
    o[2] = (short)f2bf(a.z); o[3] = (short)f2bf(a.w);
    o[4] = (short)f2bf(d.x); o[5] = (short)f2bf(d.y);
    o[6] = (short)f2bf(d.z); o[7] = (short)f2bf(d.w);
    *(short8*)(xb16 + i8) = o;
  }
}

// ---------------- fused per-(window,head,type) QKV + attention ----------------
// 8 waves; wave w owns token rows w*16..w*16+15 end-to-end.
// Phase A: u0..2 W-frags from LDS (fragment order, conflict-free); u3..5
// W-frags from global with parity-reg prefetch; x from global (bf16 if XB)
// with dist-2 reg prefetch. 2 barriers/block. 3 blocks/CU.

template<bool XB>
__global__ __launch_bounds__(512, 6) void qkv_attn(
    const float* __restrict__ xf,
    const unsigned short* __restrict__ xb16,
    const unsigned short* __restrict__ Wsb,
    const unsigned short* __restrict__ Wmb,
    const float* __restrict__ posW,
    const float* __restrict__ bias_t,
    unsigned short* __restrict__ xcat)
{
  __shared__ unsigned short Wl[12288];             // 24576 B: 24 segs x 1KB (u 0..2)
  __shared__ unsigned short Qsh[128 * 40];         // 10240 B
  __shared__ unsigned short Ksh[128 * 40];         // 10240 B
  __shared__ unsigned short VT[32 * 136];          // 8704 B [d][token]
  unsigned short* Psh = Wl;                        // P aliases W (dead after Phase A)

  // decode: XCD = kblk%8 = b%8 -> all 16 (head,type) blocks of a window on 1 XCD
  const int kblk = blockIdx.x;
  const int b    = (kblk & 7) | ((kblk >> 7) << 3);
  const int g    = (kblk >> 3) & 15;
  const int h    = g >> 1;
  const bool self = (g & 1) == 0;

  const int tid = threadIdx.x, w = tid >> 6, lane = tid & 63;
  const int lr = lane & 15, lk = lane >> 4;
  const unsigned short* Wb = self ? Wsb : Wmb;

  // ---- stage W u0..2 in FRAGMENT ORDER: seg s=(u*8+kc), 1KB each ----
  #pragma unroll
  for (int i = 0; i < 3; ++i) {
    int s  = w * 3 + i;                            // 0..23
    int u  = s >> 3, kc = s & 7;
    int o  = u >> 1, nt = u & 1;
    gload_lds16((const char*)Wb + (size_t)(o * 256 + h * 32 + nt * 16 + lr) * 512
                                + kc * 64 + lk * 16,
                (char*)Wl + s * 1024 + lane * 16);
  }

  // ---- global W frags for u3..5 (parity-reg prefetch) ----
  const unsigned short* wgbase[3];
  #pragma unroll
  for (int i = 0; i < 3; ++i) {
    int u = 3 + i, o = u >> 1, nt = u & 1;
    wgbase[i] = Wb + (size_t)(o * 256 + h * 32 + nt * 16 + lr) * 256 + lk * 8;
  }
  short8 wfg[2][3];
  #pragma unroll
  for (int i = 0; i < 3; ++i) wfg[0][i] = *(const short8*)(wgbase[i]);

  // ---- x: dist-2 register prefetch (rows m0..m0+15 disjoint per wave) ----
  const int m0 = w * 16;
  const float*          xrowf = xf   + (size_t)((b * 128 + m0 + lr) * 256 + lk * 8);
  const unsigned short* xrowb = xb16 + (size_t)((b * 128 + m0 + lr) * 256 + lk * 8);

  float4 xrf[2][2];
  short8 xrb[2];
  if (XB) {
    xrb[0] = *(const short8*)(xrowb);
    xrb[1] = *(const short8*)(xrowb + 32);
  } else {
    xrf[0][0] = *(const float4*)(xrowf);
    xrf[0][1] = *(const float4*)(xrowf + 4);
    xrf[1][0] = *(const float4*)(xrowf + 32);
    xrf[1][1] = *(const float4*)(xrowf + 36);
  }

  __syncthreads();   // barrier 1: W staged (drains vmcnt incl. prefetches)

  // ======== Phase A: wave computes rows m0..m0+15 of [Q|K|V] (96 cols) ====
  f32x4 acc[6];
  #pragma unroll
  for (int u = 0; u < 6; ++u) acc[u] = f32x4{0.f, 0.f, 0.f, 0.f};

  const char* wfrag = (const char*)Wl + lane * 16;

  #pragma unroll
  for (int kc = 0; kc < 8; ++kc) {
    if (kc + 1 < 8) {
      #pragma unroll
      for (int i = 0; i < 3; ++i)
        wfg[(kc + 1) & 1][i] = *(const short8*)(wgbase[i] + (kc + 1) * 32);
    }
    bf16x8 af;
    if (XB) {
      af = __builtin_bit_cast(bf16x8, xrb[kc & 1]);
      if (kc + 2 < 8) xrb[kc & 1] = *(const short8*)(xrowb + (kc + 2) * 32);
    } else {
      float4 a = xrf[kc & 1][0], d = xrf[kc & 1][1];
      if (kc + 2 < 8) {
        xrf[kc & 1][0] = *(const float4*)(xrowf + (kc + 2) * 32);
        xrf[kc & 1][1] = *(const float4*)(xrowf + (kc + 2) * 32 + 4);
      }
      af[0] = (__bf16)a.x; af[1] = (__bf16)a.y; af[2] = (__bf16)a.z; af[3] = (__bf16)a.w;
      af[4] = (__bf16)d.x; af[5] = (__bf16)d.y; af[6] = (__bf16)d.z; af[7] = (__bf16)d.w;
    }
    __builtin_amdgcn_s_setprio(1);
    #pragma unroll
    for (int u = 0; u < 3; ++u) {
      bf16x8 wf = *(const bf16x8*)(wfrag + ((u * 8 + kc) << 10));
      acc[u] = __builtin_amdgcn_mfma_f32_16x16x32_bf16(af, wf, acc[u], 0, 0, 0);
    }
    #pragma unroll
    for (int i = 0; i < 3; ++i)
      acc[3 + i] = __builtin_amdgcn_mfma_f32_16x16x32_bf16(
          af, __builtin_bit_cast(bf16x8, wfg[kc & 1][i]), acc[3 + i], 0, 0, 0);
    __builtin_amdgcn_s_setprio(0);
  }

  // epilogue: C layout row=(lane>>4)*4+r, col=lane&15
  #pragma unroll
  for (int u = 0; u < 6; ++u) {
    const int o = u >> 1, nt = u & 1;
    #pragma unroll
    for (int r = 0; r < 4; ++r) {
      int row  = m0 + lk * 4 + r;                  // token
      int dcol = nt * 16 + lr;                     // d within 32
      float v = acc[u][r];
      if (!self) v += posW[row * 768 + o * 256 + h * 32 + dcol];
      if (o == 2)      VT[dcol * 136 + row] = f2bf(v);
      else if (o == 0) Qsh[row * 40 + dcol] = f2bf(v);
      else             Ksh[row * 40 + dcol] = f2bf(v);
    }
  }
  __syncthreads();   // barrier 2: QKV visible; Wl dead -> Psh usable

  if (self) {
    // ======== self attention (128 keys, +bias; exp2, scale pre-folded) ========
    f32x4 sc[8];
    bf16x8 qa = *(const bf16x8*)&Qsh[(m0 + lr) * 40 + lk * 8];
    __builtin_amdgcn_s_setprio(1);
    #pragma unroll
    for (int nf = 0; nf < 8; ++nf) {
      bf16x8 kb = *(const bf16x8*)&Ksh[(nf * 16 + lr) * 40 + lk * 8];
      sc[nf] = __builtin_amdgcn_mfma_f32_16x16x32_bf16(qa, kb,
                                                       f32x4{0.f,0.f,0.f,0.f}, 0, 0, 0);
    }
    __builtin_amdgcn_s_setprio(0);
    const float* bt = bias_t + (size_t)h * 16384 + (m0 + lk * 4) * 128;
    float rsum[4] = {0.f, 0.f, 0.f, 0.f};
    #pragma unroll
    for (int nf = 0; nf < 8; ++nf)
      #pragma unroll
      for (int r = 0; r < 4; ++r) {
        float p = exp2f(sc[nf][r] + bt[r * 128 + nf * 16 + lr]);
        rsum[r] += p;
        sc[nf][r] = p;
      }
    float rs[4];
    #pragma unroll
    for (int r = 0; r < 4; ++r) {
      float t = rsum[r];
      #pragma unroll
      for (int dd = 1; dd < 16; dd <<= 1) t += __shfl_xor(t, dd, 64);
      rs[r] = 1.f / t;
    }
    f32x4 oc[2];
    oc[0] = f32x4{0.f,0.f,0.f,0.f}; oc[1] = f32x4{0.f,0.f,0.f,0.f};
    #pragma unroll
    for (int c = 0; c < 4; ++c) {                  // 32-key chunks, P wave-private
      #pragma unroll
      for (int nf2 = 0; nf2 < 2; ++nf2)
        #pragma unroll
        for (int r = 0; r < 4; ++r)
          Psh[(m0 + lk * 4 + r) * 40 + nf2 * 16 + lr] = f2bf(sc[c * 2 + nf2][r]);
      bf16x8 pa = *(const bf16x8*)&Psh[(m0 + lr) * 40 + lk * 8];
      #pragma unroll
      for (int nt = 0; nt < 2; ++nt) {
        bf16x8 vb = *(const bf16x8*)&VT[(nt * 16 + lr) * 136 + c * 32 + lk * 8];
        oc[nt] = __builtin_amdgcn_mfma_f32_16x16x32_bf16(pa, vb, oc[nt], 0, 0, 0);
      }
    }
    #pragma unroll
    for (int nt = 0; nt < 2; ++nt)
      #pragma unroll
      for (int r = 0; r < 4; ++r) {
        size_t row = (size_t)b * 128 + m0 + lk * 4 + r;
        xcat[row * 512 + 256 + h * 32 + nt * 16 + lr] = f2bf(oc[nt][r] * rs[r]);
      }
  } else {
    // ======== mutual attention (half swap, 64 keys, no bias) ========
    const int q0   = (w < 4) ? 64 + m0 : m0 - 64;  // out rows 0..63 use q2; 64..127 q1
    const int koff = (w < 4) ? 0 : 64;             // k1/v1 vs k2/v2
    f32x4 sc2[4];
    bf16x8 qa = *(const bf16x8*)&Qsh[(q0 + lr) * 40 + lk * 8];
    __builtin_amdgcn_s_setprio(1);
    #pragma unroll
    for (int nf = 0; nf < 4; ++nf) {
      bf16x8 kb = *(const bf16x8*)&Ksh[(koff + nf * 16 + lr) * 40 + lk * 8];
      sc2[nf] = __builtin_amdgcn_mfma_f32_16x16x32_bf16(qa, kb,
                                                        f32x4{0.f,0.f,0.f,0.f}, 0, 0, 0);
    }
    __builtin_amdgcn_s_setprio(0);
    float rsum2[4] = {0.f, 0.f, 0.f, 0.f};
    #pragma unroll
    for (int nf = 0; nf < 4; ++nf)
      #pragma unroll
      for (int r = 0; r < 4; ++r) {
        float p = exp2f(sc2[nf][r]);
        rsum2[r] += p;
        sc2[nf][r] = p;
      }
    float rs2[4];
    #pragma unroll
    for (int r = 0; r < 4; ++r) {
      float t = rsum2[r];
      #pragma unroll
      for (int dd = 1; dd < 16; dd <<= 1) t += __shfl_xor(t, dd, 64);
      rs2[r] = 1.f / t;
    }
    f32x4 oc[2];
    oc[0] = f32x4{0.f,0.f,0.f,0.f}; oc[1] = f32x4{0.f,0.f,0.f,0.f};
    #pragma unroll
    for (int c = 0; c < 2; ++c) {
      #pragma unroll
      for (int nf2 = 0; nf2 < 2; ++nf2)
        #pragma unroll
        for (int r = 0; r < 4; ++r)
          Psh[(m0 + lk * 4 + r) * 40 + nf2 * 16 + lr] = f2bf(sc2[c * 2 + nf2][r]);
      bf16x8 pa = *(const bf16x8*)&Psh[(m0 + lr) * 40 + lk * 8];
      #pragma unroll
      for (int nt = 0; nt < 2; ++nt) {
        bf16x8 vb = *(const bf16x8*)&VT[(nt * 16 + lr) * 136 + koff + c * 32 + lk * 8];
        oc[nt] = __builtin_amdgcn_mfma_f32_16x16x32_bf16(pa, vb, oc[nt], 0, 0, 0);
      }
    }
    #pragma unroll
    for (int nt = 0; nt < 2; ++nt)
      #pragma unroll
      for (int r = 0; r < 4; ++r) {
        size_t row = (size_t)b * 128 + m0 + lk * 4 + r;
        xcat[row * 512 + h * 32 + nt * 16 + lr] = f2bf(oc[nt][r] * rs2[r]);
      }
  }
}

// ---------------- in-place projection GEMM (unchanged, proven) ----------------
// out[262144][256] f32 = xcat[262144][512] bf16 @ Wpb[256][512]^T + bp.
// xcat and out alias (d_out); row-tiles are block-exclusive.

__global__ __launch_bounds__(512, 2) void proj_kernel(
    const unsigned short* __restrict__ xcat,
    const unsigned short* __restrict__ Wpb,
    const float* __restrict__ bp,
    float* __restrict__ out)
{
  __shared__ unsigned short Alds[2][128 * 64];     // 2 x 16 KB
  __shared__ unsigned short Blds[2][256 * 64];     // 2 x 32 KB

  const int tid = threadIdx.x, w = tid >> 6, lane = tid & 63;
  const int lr = lane & 15, lk = lane >> 4;
  const int wr = w >> 2, wc = w & 3;               // 2 x 4 wave grid
  const size_t m0 = (size_t)blockIdx.x * 128;

  f32x4 acc[4][4];
  #pragma unroll
  for (int i = 0; i < 4; ++i)
    #pragma unroll
    for (int j = 0; j < 4; ++j) acc[i][j] = f32x4{0.f, 0.f, 0.f, 0.f};

  auto stage = [&](int buf, int k0) {
    #pragma unroll
    for (int i = 0; i < 2; ++i) {                  // A: 128 x 64 bf16
      int L = (i * 512 + tid) * 16;
      int row = L >> 7;
      int inrow = (L & 127) ^ ((row & 7) << 4);
      gload_lds16((const char*)xcat + (m0 + row) * 1024 + k0 * 2 + inrow,
                  (char*)&Alds[buf][0] + L);
    }
    #pragma unroll
    for (int i = 0; i < 4; ++i) {                  // B: 256 x 64 bf16
      int L = (i * 512 + tid) * 16;
      int row = L >> 7;
      int inrow = (L & 127) ^ ((row & 7) << 4);
      gload_lds16((const char*)Wpb + (size_t)row * 1024 + k0 * 2 + inrow,
                  (char*)&Blds[buf][0] + L);
    }
  };

  stage(0, 0);
  __syncthreads();
  int cur = 0;
  for (int t = 0; t < 8; ++t) {
    if (t < 7) stage(cur ^ 1, (t + 1) * 64);
    const char* At = (const char*)&Alds[cur][0];
    const char* Bt = (const char*)&Blds[cur][0];
    #pragma unroll
    for (int kk = 0; kk < 2; ++kk) {
      bf16x8 af[4], bfr[4];
      #pragma unroll
      for (int mt = 0; mt < 4; ++mt) {
        int row = wr * 64 + mt * 16 + lr;
        int off = (row * 128 + kk * 64 + lk * 16) ^ ((row & 7) << 4);
        af[mt] = *(const bf16x8*)(At + off);
      }
      #pragma unroll
      for (int nt = 0; nt < 4; ++nt) {
        int row = wc * 64 + nt * 16 + lr;
        int off = (row * 128 + kk * 64 + lk * 16) ^ ((row & 7) << 4);
        bfr[nt] = *(const bf16x8*)(Bt + off);
      }
      #pragma unroll
      for (int mt = 0; mt < 4; ++mt)
        #pragma unroll
        for (int nt = 0; nt < 4; ++nt)
          acc[mt][nt] = __builtin_amdgcn_mfma_f32_16x16x32_bf16(af[mt], bfr[nt],
                                                                acc[mt][nt], 0, 0, 0);
    }
    __syncthreads();
    cur ^= 1;
  }

  #pragma unroll
  for (int mt = 0; mt < 4; ++mt)
    #pragma unroll
    for (int r = 0; r < 4; ++r) {
      size_t grow = m0 + wr * 64 + mt * 16 + lk * 4 + r;
      #pragma unroll
      for (int nt = 0; nt < 4; ++nt) {
        int gcol = wc * 64 + nt * 16 + lr;
        out[grow * 256 + gcol] = acc[mt][nt][r] + bp[gcol];
      }
    }
}

// ---------------- launch ----------------

extern "C" void kernel_launch(void* const* d_in, const int* in_sizes, int n_in,
                              void* d_out, int out_size, void* d_ws, size_t ws_size,
                              hipStream_t stream) {
  (void)in_sizes; (void)n_in; (void)out_size;
  const float* x   = (const float*)d_in[0];
  const float* rpb = (const float*)d_in[1];
  const float* Wqs = (const float*)d_in[2];
  const float* Wqm = (const float*)d_in[3];
  const float* Wp  = (const float*)d_in[4];
  const float* bp  = (const float*)d_in[5];
  char* ws = (char*)d_ws;

  // workspace: tables (2,097,152 bytes) + optional xb16 (134,217,728 bytes)
  size_t off = 0;
  float* pos_t  = (float*)(ws + off); off += 32768ull  * 4;
  float* posW   = (float*)(ws + off); off += 98304ull  * 4;
  float* bias_t = (float*)(ws + off); off += 131072ull * 4;
  unsigned short* Wsb = (unsigned short*)(ws + off); off += 196608ull * 2;
  unsigned short* Wmb = (unsigned short*)(ws + off); off += 196608ull * 2;
  unsigned short* Wpb = (unsigned short*)(ws + off); off += 131072ull * 2;
  if (ws_size < off) return;                        // 2 MB — should always fit
  unsigned short* xb16 = (unsigned short*)(ws + off);
  const bool use_xb = (ws_size >= off + 67108864ull * 2);   // full x in bf16

  // xcat (bf16 [262144][512] = 268,435,456 B) lives in d_out; proj runs in-place.
  unsigned short* xcat = (unsigned short*)d_out;

  pos_kernel <<<dim3(128),  dim3(256), 0, stream>>>(pos_t);
  bias_kernel<<<dim3(512),  dim3(256), 0, stream>>>(rpb, bias_t);
  wconv_kernel<<<dim3(2048), dim3(256), 0, stream>>>(Wqs, Wqm, Wp, Wsb, Wmb, Wpb);
  posw_kernel<<<dim3(384),  dim3(256), 0, stream>>>(pos_t, Wqm, posW);

  if (use_xb) {
    xconv_kernel<<<dim3(8192), dim3(256), 0, stream>>>(x, xb16);
    qkv_attn<true><<<dim3(32768), dim3(512), 0, stream>>>(
        x, xb16, Wsb, Wmb, posW, bias_t, xcat);
  } else {
    qkv_attn<false><<<dim3(32768), dim3(512), 0, stream>>>(
        x, xb16, Wsb, Wmb, posW, bias_t, xcat);
  }

  proj_kernel<<<dim3(2048), dim3(512), 0, stream>>>(xcat, Wpb, bp, (float*)d_out);
}

// Round 11
// 1199.392 us; speedup vs baseline: 1.1765x; 1.1765x over previous
//
#include <hip/hip_runtime.h>

// ---------------------------------------------------------------------------
// WindowAttention fused pipeline for MI355X (gfx950)
//   B=2048 windows, N=128 tokens, C=256, H=8 heads, hd=32
// Round-11 = round-9 structure + ONE change: Phase A re-tiled 2m x 3n per
// wave (wave (mg,ng) computes rows mg*32..+31 x units ng*3..+2). W-fragment
// LDS reads halve (48 -> 24/wave, each reused by 2 MFMAs); x loads double
// but ride the idle VMEM pipe (xb16 L2-resident). Keeps (512,4) -- r10's
// regression was the (512,6) VGPR cap killing prefetch regs.
// exp2 folding kept from r10 (passed). Fragment-order W staging unchanged.
// xcat (bf16) lives in d_out; proj GEMM runs in-place (proven path).
// ---------------------------------------------------------------------------

typedef __attribute__((ext_vector_type(8))) short     short8;
typedef __attribute__((ext_vector_type(8))) __bf16    bf16x8;
typedef __attribute__((ext_vector_type(4))) float     f32x4;

#define LOG2E 1.4426950408889634f

__device__ __forceinline__ unsigned short f2bf(float f) {
  return __builtin_bit_cast(unsigned short, (__bf16)f);   // native cvt, RTNE
}

__device__ __forceinline__ void gload_lds16(const void* g, void* l) {
  __builtin_amdgcn_global_load_lds((const __attribute__((address_space(1))) void*)g,
                                   (__attribute__((address_space(3))) void*)l, 16, 0, 0);
}

// ---------------- precompute kernels ----------------

__global__ void pos_kernel(float* __restrict__ pos_t) {
  int e = blockIdx.x * 256 + threadIdx.x;          // 32768 = 128*256
  int t = e >> 8, c = e & 255;
  int p = t & 63;                                   // tiled (1,2,1)
  const float norm = 6.28318530717958647692f / 8.000001f;  // scale/(8+1e-6)
  float yn = (float)((p >> 3) + 1) * norm;
  float xn = (float)((p & 7) + 1) * norm;
  int cc = c & 127;
  int m  = cc >> 1;
  float v = ((c < 128) ? yn : xn) * __expf(-(float)m * 0.14391156831f);
  pos_t[e] = (cc & 1) ? cosf(v) : sinf(v);
}

__global__ void posw_kernel(const float* __restrict__ pos_t,
                            const float* __restrict__ Wm,
                            float* __restrict__ posW) {
  int e = blockIdx.x * 256 + threadIdx.x;          // 98304 = 128*768
  int t = e / 768, c = e - t * 768;
  const float4* pr = (const float4*)(pos_t + t * 256);
  const float4* wr = (const float4*)(Wm + (size_t)c * 256);
  float acc = 0.f;
  #pragma unroll 8
  for (int k = 0; k < 64; ++k) {
    float4 p = pr[k], w = wr[k];
    acc += p.x * w.x + p.y * w.y + p.z * w.z + p.w * w.w;
  }
  if (c < 256) acc *= 0.17677669529663688f * LOG2E;  // fold attn scale + log2e into Q
  posW[e] = acc;
}

__global__ void bias_kernel(const float* __restrict__ rpb, float* __restrict__ bias_t) {
  int e = blockIdx.x * 256 + threadIdx.x;          // 131072 = 8*128*128
  int h = e >> 14, i = (e >> 7) & 127, j = e & 127;
  int di = i >> 6, hi = (i >> 3) & 7, wi = i & 7;
  int dj = j >> 6, hj = (j >> 3) & 7, wj = j & 7;
  int idx = (di - dj + 1) * 225 + (hi - hj + 7) * 15 + (wi - wj + 7);
  bias_t[e] = rpb[idx * 8 + h] * LOG2E;            // folded for exp2
}

__global__ void wconv_kernel(const float* __restrict__ Ws, const float* __restrict__ Wm,
                             const float* __restrict__ Wp,
                             unsigned short* __restrict__ Wsb,
                             unsigned short* __restrict__ Wmb,
                             unsigned short* __restrict__ Wpb) {
  int e = blockIdx.x * 256 + threadIdx.x;          // 524288
  const float qs = 0.17677669529663688f * LOG2E;   // 32^-0.5 * log2e into Q rows
  if (e < 196608) {
    float v = Ws[e]; if (e < 65536) v *= qs;       // rows 0..255 = Q
    Wsb[e] = f2bf(v);
  } else if (e < 393216) {
    int i = e - 196608;
    float v = Wm[i]; if (i < 65536) v *= qs;
    Wmb[i] = f2bf(v);
  } else {
    Wpb[e - 393216] = f2bf(Wp[e - 393216]);
  }
}

__global__ void xconv_kernel(const float* __restrict__ x, unsigned short* __restrict__ xb16) {
  // x has 67,108,864 f32 elements (2048*128*256); 8 per thread, grid-stride.
  for (size_t i8 = ((size_t)blockIdx.x * 256 + threadIdx.x) * 8; i8 < 67108864ull;
       i8 += (size_t)gridDim.x * 256 * 8) {
    float4 a = *(const float4*)(x + i8);
    float4 d = *(const float4*)(x + i8 + 4);
    short8 o;
    o[0] = (short)f2bf(a.x); o[1] = (short)f2bf(a.y);
    o[2] = (short)f2bf(a.z); o[3] = (short)f2bf(a.w);
    o[4] = (short)f2bf(d.x); o[5] = (short)f2bf(d.y);
    o[6] = (short)f2bf(d.z); o[7] = (short)f2bf(d.w);
    *(short8*)(xb16 + i8) = o;
  }
}

// ---------------- fused per-(window,head,type) QKV + attention ----------------
// Phase A: wave (mg=w>>1, ng=w&1) computes rows mg*32..+31 x units ng*3..+2.
// W frags from LDS (fragment order, 24 reads/wave, each feeds 2 MFMAs);
// x from global bf16 with dist-2 reg prefetch. 2 barriers/block.
// Attention: wave w owns rows w*16..+15 (decoupled from Phase-A mapping).

template<bool XB>
__global__ __launch_bounds__(512, 4) void qkv_attn(
    const float* __restrict__ xf,
    const unsigned short* __restrict__ xb16,
    const unsigned short* __restrict__ Wsb,
    const unsigned short* __restrict__ Wmb,
    const float* __restrict__ posW,
    const float* __restrict__ bias_t,
    unsigned short* __restrict__ xcat)
{
  __shared__ unsigned short Wl[24576];             // 49152 B: 48 segs x 1KB (frag order)
  __shared__ unsigned short Qsh[128 * 40];         // 10240 B
  __shared__ unsigned short Ksh[128 * 40];         // 10240 B
  __shared__ unsigned short VT[32 * 136];          // 8704 B [d][token]
  unsigned short* Psh = Wl;                        // P aliases W (dead after Phase A)

  // decode: XCD = kblk%8 = b%8 -> all 16 (head,type) blocks of a window on 1 XCD
  const int kblk = blockIdx.x;
  const int b    = (kblk & 7) | ((kblk >> 7) << 3);
  const int g    = (kblk >> 3) & 15;
  const int h    = g >> 1;
  const bool self = (g & 1) == 0;

  const int tid = threadIdx.x, w = tid >> 6, lane = tid & 63;
  const int lr = lane & 15, lk = lane >> 4;
  const unsigned short* Wb = self ? Wsb : Wmb;

  // ---- stage W slice in FRAGMENT ORDER: seg s=(u*8+kc), 1KB each (as r9) ----
  #pragma unroll
  for (int i = 0; i < 6; ++i) {
    int s  = w * 6 + i;
    int u  = s >> 3, kc = s & 7;
    int o  = u >> 1, nt = u & 1;
    gload_lds16((const char*)Wb + (size_t)(o * 256 + h * 32 + nt * 16 + lr) * 512
                                + kc * 64 + lk * 16,
                (char*)Wl + s * 1024 + lane * 16);
  }

  // ---- Phase-A tiling: mg rows, ng unit-group ----
  const int mg = w >> 1, ng = w & 1;

  // x rows for the two m-tiles of this wave (dist-2 parity prefetch)
  const float*          xrf0 = xf   + (size_t)((b * 128 + mg * 32 + lr) * 256 + lk * 8);
  const float*          xrf1 = xrf0 + 16 * 256;
  const unsigned short* xrb0 = xb16 + (size_t)((b * 128 + mg * 32 + lr) * 256 + lk * 8);
  const unsigned short* xrb1 = xrb0 + 16 * 256;

  short8 xrb[2][2];                                 // [mt][parity]
  if (XB) {
    xrb[0][0] = *(const short8*)(xrb0);
    xrb[1][0] = *(const short8*)(xrb1);
    xrb[0][1] = *(const short8*)(xrb0 + 32);
    xrb[1][1] = *(const short8*)(xrb1 + 32);
  }

  __syncthreads();   // barrier 1: W staged (drains vmcnt incl. prefetches)

  // ======== Phase A: 2 m-tiles x 3 units, K=256 ========
  f32x4 acc[3][2];
  #pragma unroll
  for (int i = 0; i < 3; ++i) {
    acc[i][0] = f32x4{0.f, 0.f, 0.f, 0.f};
    acc[i][1] = f32x4{0.f, 0.f, 0.f, 0.f};
  }

  const char* wfrag = (const char*)Wl + ng * 24576 + lane * 16;  // ng's 3-unit half

  #pragma unroll
  for (int kc = 0; kc < 8; ++kc) {
    bf16x8 af0, af1;
    if (XB) {
      af0 = __builtin_bit_cast(bf16x8, xrb[0][kc & 1]);
      af1 = __builtin_bit_cast(bf16x8, xrb[1][kc & 1]);
      if (kc + 2 < 8) {
        xrb[0][kc & 1] = *(const short8*)(xrb0 + (kc + 2) * 32);
        xrb[1][kc & 1] = *(const short8*)(xrb1 + (kc + 2) * 32);
      }
    } else {
      float4 a0 = *(const float4*)(xrf0 + kc * 32);
      float4 d0 = *(const float4*)(xrf0 + kc * 32 + 4);
      float4 a1 = *(const float4*)(xrf1 + kc * 32);
      float4 d1 = *(const float4*)(xrf1 + kc * 32 + 4);
      af0[0] = (__bf16)a0.x; af0[1] = (__bf16)a0.y; af0[2] = (__bf16)a0.z; af0[3] = (__bf16)a0.w;
      af0[4] = (__bf16)d0.x; af0[5] = (__bf16)d0.y; af0[6] = (__bf16)d0.z; af0[7] = (__bf16)d0.w;
      af1[0] = (__bf16)a1.x; af1[1] = (__bf16)a1.y; af1[2] = (__bf16)a1.z; af1[3] = (__bf16)a1.w;
      af1[4] = (__bf16)d1.x; af1[5] = (__bf16)d1.y; af1[6] = (__bf16)d1.z; af1[7] = (__bf16)d1.w;
    }
    __builtin_amdgcn_s_setprio(1);
    #pragma unroll
    for (int i = 0; i < 3; ++i) {
      bf16x8 wf = *(const bf16x8*)(wfrag + ((i * 8 + kc) << 10));
      acc[i][0] = __builtin_amdgcn_mfma_f32_16x16x32_bf16(af0, wf, acc[i][0], 0, 0, 0);
      acc[i][1] = __builtin_amdgcn_mfma_f32_16x16x32_bf16(af1, wf, acc[i][1], 0, 0, 0);
    }
    __builtin_amdgcn_s_setprio(0);
  }

  // epilogue: C layout row=(lane>>4)*4+r, col=lane&15
  #pragma unroll
  for (int i = 0; i < 3; ++i) {
    const int u = ng * 3 + i;
    const int o = u >> 1, nt = u & 1;
    #pragma unroll
    for (int mt = 0; mt < 2; ++mt)
      #pragma unroll
      for (int r = 0; r < 4; ++r) {
        int row  = mg * 32 + mt * 16 + lk * 4 + r; // token
        int dcol = nt * 16 + lr;                   // d within 32
        float v = acc[i][mt][r];
        if (!self) v += posW[row * 768 + o * 256 + h * 32 + dcol];
        if (o == 2)      VT[dcol * 136 + row] = f2bf(v);
        else if (o == 0) Qsh[row * 40 + dcol] = f2bf(v);
        else             Ksh[row * 40 + dcol] = f2bf(v);
      }
  }
  __syncthreads();   // barrier 2: QKV visible; Wl dead -> Psh usable

  const int m0 = w * 16;                            // attention row ownership

  if (self) {
    // ======== self attention (128 keys, +bias; exp2, scale pre-folded) ========
    f32x4 sc[8];
    bf16x8 qa = *(const bf16x8*)&Qsh[(m0 + lr) * 40 + lk * 8];
    __builtin_amdgcn_s_setprio(1);
    #pragma unroll
    for (int nf = 0; nf < 8; ++nf) {
      bf16x8 kb = *(const bf16x8*)&Ksh[(nf * 16 + lr) * 40 + lk * 8];
      sc[nf] = __builtin_amdgcn_mfma_f32_16x16x32_bf16(qa, kb,
                                                       f32x4{0.f,0.f,0.f,0.f}, 0, 0, 0);
    }
    __builtin_amdgcn_s_setprio(0);
    const float* bt = bias_t + (size_t)h * 16384 + (m0 + lk * 4) * 128;
    float rsum[4] = {0.f, 0.f, 0.f, 0.f};
    #pragma unroll
    for (int nf = 0; nf < 8; ++nf)
      #pragma unroll
      for (int r = 0; r < 4; ++r) {
        float p = exp2f(sc[nf][r] + bt[r * 128 + nf * 16 + lr]);
        rsum[r] += p;
        sc[nf][r] = p;
      }
    float rs[4];
    #pragma unroll
    for (int r = 0; r < 4; ++r) {
      float t = rsum[r];
      #pragma unroll
      for (int dd = 1; dd < 16; dd <<= 1) t += __shfl_xor(t, dd, 64);
      rs[r] = 1.f / t;
    }
    f32x4 oc[2];
    oc[0] = f32x4{0.f,0.f,0.f,0.f}; oc[1] = f32x4{0.f,0.f,0.f,0.f};
    #pragma unroll
    for (int c = 0; c < 4; ++c) {                  // 32-key chunks, P wave-private
      #pragma unroll
      for (int nf2 = 0; nf2 < 2; ++nf2)
        #pragma unroll
        for (int r = 0; r < 4; ++r)
          Psh[(m0 + lk * 4 + r) * 40 + nf2 * 16 + lr] = f2bf(sc[c * 2 + nf2][r]);
      bf16x8 pa = *(const bf16x8*)&Psh[(m0 + lr) * 40 + lk * 8];
      #pragma unroll
      for (int nt = 0; nt < 2; ++nt) {
        bf16x8 vb = *(const bf16x8*)&VT[(nt * 16 + lr) * 136 + c * 32 + lk * 8];
        oc[nt] = __builtin_amdgcn_mfma_f32_16x16x32_bf16(pa, vb, oc[nt], 0, 0, 0);
      }
    }
    #pragma unroll
    for (int nt = 0; nt < 2; ++nt)
      #pragma unroll
      for (int r = 0; r < 4; ++r) {
        size_t row = (size_t)b * 128 + m0 + lk * 4 + r;
        xcat[row * 512 + 256 + h * 32 + nt * 16 + lr] = f2bf(oc[nt][r] * rs[r]);
      }
  } else {
    // ======== mutual attention (half swap, 64 keys, no bias) ========
    const int q0   = (w < 4) ? 64 + m0 : m0 - 64;  // out rows 0..63 use q2; 64..127 q1
    const int koff = (w < 4) ? 0 : 64;             // k1/v1 vs k2/v2
    f32x4 sc2[4];
    bf16x8 qa = *(const bf16x8*)&Qsh[(q0 + lr) * 40 + lk * 8];
    __builtin_amdgcn_s_setprio(1);
    #pragma unroll
    for (int nf = 0; nf < 4; ++nf) {
      bf16x8 kb = *(const bf16x8*)&Ksh[(koff + nf * 16 + lr) * 40 + lk * 8];
      sc2[nf] = __builtin_amdgcn_mfma_f32_16x16x32_bf16(qa, kb,
                                                        f32x4{0.f,0.f,0.f,0.f}, 0, 0, 0);
    }
    __builtin_amdgcn_s_setprio(0);
    float rsum2[4] = {0.f, 0.f, 0.f, 0.f};
    #pragma unroll
    for (int nf = 0; nf < 4; ++nf)
      #pragma unroll
      for (int r = 0; r < 4; ++r) {
        float p = exp2f(sc2[nf][r]);
        rsum2[r] += p;
        sc2[nf][r] = p;
      }
    float rs2[4];
    #pragma unroll
    for (int r = 0; r < 4; ++r) {
      float t = rsum2[r];
      #pragma unroll
      for (int dd = 1; dd < 16; dd <<= 1) t += __shfl_xor(t, dd, 64);
      rs2[r] = 1.f / t;
    }
    f32x4 oc[2];
    oc[0] = f32x4{0.f,0.f,0.f,0.f}; oc[1] = f32x4{0.f,0.f,0.f,0.f};
    #pragma unroll
    for (int c = 0; c < 2; ++c) {
      #pragma unroll
      for (int nf2 = 0; nf2 < 2; ++nf2)
        #pragma unroll
        for (int r = 0; r < 4; ++r)
          Psh[(m0 + lk * 4 + r) * 40 + nf2 * 16 + lr] = f2bf(sc2[c * 2 + nf2][r]);
      bf16x8 pa = *(const bf16x8*)&Psh[(m0 + lr) * 40 + lk * 8];
      #pragma unroll
      for (int nt = 0; nt < 2; ++nt) {
        bf16x8 vb = *(const bf16x8*)&VT[(nt * 16 + lr) * 136 + koff + c * 32 + lk * 8];
        oc[nt] = __builtin_amdgcn_mfma_f32_16x16x32_bf16(pa, vb, oc[nt], 0, 0, 0);
      }
    }
    #pragma unroll
    for (int nt = 0; nt < 2; ++nt)
      #pragma unroll
      for (int r = 0; r < 4; ++r) {
        size_t row = (size_t)b * 128 + m0 + lk * 4 + r;
        xcat[row * 512 + h * 32 + nt * 16 + lr] = f2bf(oc[nt][r] * rs2[r]);
      }
  }
}

// ---------------- in-place projection GEMM (unchanged, proven) ----------------
// out[262144][256] f32 = xcat[262144][512] bf16 @ Wpb[256][512]^T + bp.
// xcat and out alias (d_out); row-tiles are block-exclusive.

__global__ __launch_bounds__(512, 2) void proj_kernel(
    const unsigned short* __restrict__ xcat,
    const unsigned short* __restrict__ Wpb,
    const float* __restrict__ bp,
    float* __restrict__ out)
{
  __shared__ unsigned short Alds[2][128 * 64];     // 2 x 16 KB
  __shared__ unsigned short Blds[2][256 * 64];     // 2 x 32 KB

  const int tid = threadIdx.x, w = tid >> 6, lane = tid & 63;
  const int lr = lane & 15, lk = lane >> 4;
  const int wr = w >> 2, wc = w & 3;               // 2 x 4 wave grid
  const size_t m0 = (size_t)blockIdx.x * 128;

  f32x4 acc[4][4];
  #pragma unroll
  for (int i = 0; i < 4; ++i)
    #pragma unroll
    for (int j = 0; j < 4; ++j) acc[i][j] = f32x4{0.f, 0.f, 0.f, 0.f};

  auto stage = [&](int buf, int k0) {
    #pragma unroll
    for (int i = 0; i < 2; ++i) {                  // A: 128 x 64 bf16
      int L = (i * 512 + tid) * 16;
      int row = L >> 7;
      int inrow = (L & 127) ^ ((row & 7) << 4);
      gload_lds16((const char*)xcat + (m0 + row) * 1024 + k0 * 2 + inrow,
                  (char*)&Alds[buf][0] + L);
    }
    #pragma unroll
    for (int i = 0; i < 4; ++i) {                  // B: 256 x 64 bf16
      int L = (i * 512 + tid) * 16;
      int row = L >> 7;
      int inrow = (L & 127) ^ ((row & 7) << 4);
      gload_lds16((const char*)Wpb + (size_t)row * 1024 + k0 * 2 + inrow,
                  (char*)&Blds[buf][0] + L);
    }
  };

  stage(0, 0);
  __syncthreads();
  int cur = 0;
  for (int t = 0; t < 8; ++t) {
    if (t < 7) stage(cur ^ 1, (t + 1) * 64);
    const char* At = (const char*)&Alds[cur][0];
    const char* Bt = (const char*)&Blds[cur][0];
    #pragma unroll
    for (int kk = 0; kk < 2; ++kk) {
      bf16x8 af[4], bfr[4];
      #pragma unroll
      for (int mt = 0; mt < 4; ++mt) {
        int row = wr * 64 + mt * 16 + lr;
        int off = (row * 128 + kk * 64 + lk * 16) ^ ((row & 7) << 4);
        af[mt] = *(const bf16x8*)(At + off);
      }
      #pragma unroll
      for (int nt = 0; nt < 4; ++nt) {
        int row = wc * 64 + nt * 16 + lr;
        int off = (row * 128 + kk * 64 + lk * 16) ^ ((row & 7) << 4);
        bfr[nt] = *(const bf16x8*)(Bt + off);
      }
      #pragma unroll
      for (int mt = 0; mt < 4; ++mt)
        #pragma unroll
        for (int nt = 0; nt < 4; ++nt)
          acc[mt][nt] = __builtin_amdgcn_mfma_f32_16x16x32_bf16(af[mt], bfr[nt],
                                                                acc[mt][nt], 0, 0, 0);
    }
    __syncthreads();
    cur ^= 1;
  }

  #pragma unroll
  for (int mt = 0; mt < 4; ++mt)
    #pragma unroll
    for (int r = 0; r < 4; ++r) {
      size_t grow = m0 + wr * 64 + mt * 16 + lk * 4 + r;
      #pragma unroll
      for (int nt = 0; nt < 4; ++nt) {
        int gcol = wc * 64 + nt * 16 + lr;
        out[grow * 256 + gcol] = acc[mt][nt][r] + bp[gcol];
      }
    }
}

// ---------------- launch ----------------

extern "C" void kernel_launch(void* const* d_in, const int* in_sizes, int n_in,
                              void* d_out, int out_size, void* d_ws, size_t ws_size,
                              hipStream_t stream) {
  (void)in_sizes; (void)n_in; (void)out_size;
  const float* x   = (const float*)d_in[0];
  const float* rpb = (const float*)d_in[1];
  const float* Wqs = (const float*)d_in[2];
  const float* Wqm = (const float*)d_in[3];
  const float* Wp  = (const float*)d_in[4];
  const float* bp  = (const float*)d_in[5];
  char* ws = (char*)d_ws;

  // workspace: tables (2,097,152 bytes) + optional xb16 (134,217,728 bytes)
  size_t off = 0;
  float* pos_t  = (float*)(ws + off); off += 32768ull  * 4;
  float* posW   = (float*)(ws + off); off += 98304ull  * 4;
  float* bias_t = (float*)(ws + off); off += 131072ull * 4;
  unsigned short* Wsb = (unsigned short*)(ws + off); off += 196608ull * 2;
  unsigned short* Wmb = (unsigned short*)(ws + off); off += 196608ull * 2;
  unsigned short* Wpb = (unsigned short*)(ws + off); off += 131072ull * 2;
  if (ws_size < off) return;                        // 2 MB — should always fit
  unsigned short* xb16 = (unsigned short*)(ws + off);
  const bool use_xb = (ws_size >= off + 67108864ull * 2);   // full x in bf16

  // xcat (bf16 [262144][512] = 268,435,456 B) lives in d_out; proj runs in-place.
  unsigned short* xcat = (unsigned short*)d_out;

  pos_kernel <<<dim3(128),  dim3(256), 0, stream>>>(pos_t);
  bias_kernel<<<dim3(512),  dim3(256), 0, stream>>>(rpb, bias_t);
  wconv_kernel<<<dim3(2048), dim3(256), 0, stream>>>(Wqs, Wqm, Wp, Wsb, Wmb, Wpb);
  posw_kernel<<<dim3(384),  dim3(256), 0, stream>>>(pos_t, Wqm, posW);

  if (use_xb) {
    xconv_kernel<<<dim3(8192), dim3(256), 0, stream>>>(x, xb16);
    qkv_attn<true><<<dim3(32768), dim3(512), 0, stream>>>(
        x, xb16, Wsb, Wmb, posW, bias_t, xcat);
  } else {
    qkv_attn<false><<<dim3(32768), dim3(512), 0, stream>>>(
        x, xb16, Wsb, Wmb, posW, bias_t, xcat);
  }

  proj_kernel<<<dim3(2048), dim3(512), 0, stream>>>(xcat, Wpb, bp, (float*)d_out);
}

// Round 12
// 830.066 us; speedup vs baseline: 1.6999x; 1.4449x over previous
//
#include <hip/hip_runtime.h>

// ---------------------------------------------------------------------------
// WindowAttention fused pipeline for MI355X (gfx950)
//   B=2048 windows, N=128 tokens, C=256, H=8 heads, hd=32
// Round-12 = round-9 EXACTLY (best measured: 766us qkv_attn) plus two
// isolated, low-risk deltas:
//   (a) exp2 folding: Q-scale *= log2e (weights/posW), bias *= log2e ->
//       exp2f in softmax (proven correct in r10/r11).
//   (b) issue-early register prefetch of post-barrier global reads:
//       self: 32 bias_t values; mut: 24 posW values -- loaded into pre_r[32]
//       BEFORE barrier 1, so their L2 latency hides under Phase A instead of
//       sitting in Phase B / the epilogue (T14 issue-early).
// xcat (bf16) lives in d_out; proj GEMM runs in-place (proven path).
// ---------------------------------------------------------------------------

typedef __attribute__((ext_vector_type(8))) short     short8;
typedef __attribute__((ext_vector_type(8))) __bf16    bf16x8;
typedef __attribute__((ext_vector_type(4))) float     f32x4;

#define LOG2E 1.4426950408889634f

__device__ __forceinline__ unsigned short f2bf(float f) {
  return __builtin_bit_cast(unsigned short, (__bf16)f);   // native cvt, RTNE
}

__device__ __forceinline__ void gload_lds16(const void* g, void* l) {
  __builtin_amdgcn_global_load_lds((const __attribute__((address_space(1))) void*)g,
                                   (__attribute__((address_space(3))) void*)l, 16, 0, 0);
}

// ---------------- precompute kernels ----------------

__global__ void pos_kernel(float* __restrict__ pos_t) {
  int e = blockIdx.x * 256 + threadIdx.x;          // 32768 = 128*256
  int t = e >> 8, c = e & 255;
  int p = t & 63;                                   // tiled (1,2,1)
  const float norm = 6.28318530717958647692f / 8.000001f;  // scale/(8+1e-6)
  float yn = (float)((p >> 3) + 1) * norm;
  float xn = (float)((p & 7) + 1) * norm;
  int cc = c & 127;
  int m  = cc >> 1;
  float v = ((c < 128) ? yn : xn) * __expf(-(float)m * 0.14391156831f);
  pos_t[e] = (cc & 1) ? cosf(v) : sinf(v);
}

__global__ void posw_kernel(const float* __restrict__ pos_t,
                            const float* __restrict__ Wm,
                            float* __restrict__ posW) {
  int e = blockIdx.x * 256 + threadIdx.x;          // 98304 = 128*768
  int t = e / 768, c = e - t * 768;
  const float4* pr = (const float4*)(pos_t + t * 256);
  const float4* wr = (const float4*)(Wm + (size_t)c * 256);
  float acc = 0.f;
  #pragma unroll 8
  for (int k = 0; k < 64; ++k) {
    float4 p = pr[k], w = wr[k];
    acc += p.x * w.x + p.y * w.y + p.z * w.z + p.w * w.w;
  }
  if (c < 256) acc *= 0.17677669529663688f * LOG2E;  // fold attn scale + log2e into Q
  posW[e] = acc;
}

__global__ void bias_kernel(const float* __restrict__ rpb, float* __restrict__ bias_t) {
  int e = blockIdx.x * 256 + threadIdx.x;          // 131072 = 8*128*128
  int h = e >> 14, i = (e >> 7) & 127, j = e & 127;
  int di = i >> 6, hi = (i >> 3) & 7, wi = i & 7;
  int dj = j >> 6, hj = (j >> 3) & 7, wj = j & 7;
  int idx = (di - dj + 1) * 225 + (hi - hj + 7) * 15 + (wi - wj + 7);
  bias_t[e] = rpb[idx * 8 + h] * LOG2E;            // folded for exp2
}

__global__ void wconv_kernel(const float* __restrict__ Ws, const float* __restrict__ Wm,
                             const float* __restrict__ Wp,
                             unsigned short* __restrict__ Wsb,
                             unsigned short* __restrict__ Wmb,
                             unsigned short* __restrict__ Wpb) {
  int e = blockIdx.x * 256 + threadIdx.x;          // 524288
  const float qs = 0.17677669529663688f * LOG2E;   // 32^-0.5 * log2e into Q rows
  if (e < 196608) {
    float v = Ws[e]; if (e < 65536) v *= qs;       // rows 0..255 = Q
    Wsb[e] = f2bf(v);
  } else if (e < 393216) {
    int i = e - 196608;
    float v = Wm[i]; if (i < 65536) v *= qs;
    Wmb[i] = f2bf(v);
  } else {
    Wpb[e - 393216] = f2bf(Wp[e - 393216]);
  }
}

__global__ void xconv_kernel(const float* __restrict__ x, unsigned short* __restrict__ xb16) {
  // x has 67,108,864 f32 elements (2048*128*256); 8 per thread, grid-stride.
  for (size_t i8 = ((size_t)blockIdx.x * 256 + threadIdx.x) * 8; i8 < 67108864ull;
       i8 += (size_t)gridDim.x * 256 * 8) {
    float4 a = *(const float4*)(x + i8);
    float4 d = *(const float4*)(x + i8 + 4);
    short8 o;
    o[0] = (short)f2bf(a.x); o[1] = (short)f2bf(a.y);
    o[2] = (short)f2bf(a.z); o[3] = (short)f2bf(a.w);
    o[4] = (short)f2bf(d.x); o[5] = (short)f2bf(d.y);
    o[6] = (short)f2bf(d.z); o[7] = (short)f2bf(d.w);
    *(short8*)(xb16 + i8) = o;
  }
}

// ---------------- fused per-(window,head,type) QKV + attention ----------------
// 8 waves; wave w owns token rows w*16..w*16+15 end-to-end (r9 mapping).
// Phase A: W frags from LDS (fragment order, conflict-free), x from global
// bf16 with dist-2 reg prefetch. bias/posW prefetched to regs pre-barrier-1.
// 2 barriers/block.

template<bool XB>
__global__ __launch_bounds__(512, 4) void qkv_attn(
    const float* __restrict__ xf,
    const unsigned short* __restrict__ xb16,
    const unsigned short* __restrict__ Wsb,
    const unsigned short* __restrict__ Wmb,
    const float* __restrict__ posW,
    const float* __restrict__ bias_t,
    unsigned short* __restrict__ xcat)
{
  __shared__ unsigned short Wl[24576];             // 49152 B: 48 segs x 1KB (frag order)
  __shared__ unsigned short Qsh[128 * 40];         // 10240 B
  __shared__ unsigned short Ksh[128 * 40];         // 10240 B
  __shared__ unsigned short VT[32 * 136];          // 8704 B [d][token]
  unsigned short* Psh = Wl;                        // P aliases W (dead after Phase A)

  // decode: XCD = kblk%8 = b%8 -> all 16 (head,type) blocks of a window on 1 XCD
  const int kblk = blockIdx.x;
  const int b    = (kblk & 7) | ((kblk >> 7) << 3);
  const int g    = (kblk >> 3) & 15;
  const int h    = g >> 1;
  const bool self = (g & 1) == 0;

  const int tid = threadIdx.x, w = tid >> 6, lane = tid & 63;
  const int lr = lane & 15, lk = lane >> 4;
  const unsigned short* Wb = self ? Wsb : Wmb;
  const int m0 = w * 16;                           // this wave's rows (Phase A + attn)

  // ---- stage W slice in FRAGMENT ORDER: seg s=(u*8+kc), 1KB each ----
  #pragma unroll
  for (int i = 0; i < 6; ++i) {
    int s  = w * 6 + i;
    int u  = s >> 3, kc = s & 7;
    int o  = u >> 1, nt = u & 1;
    gload_lds16((const char*)Wb + (size_t)(o * 256 + h * 32 + nt * 16 + lr) * 512
                                + kc * 64 + lk * 16,
                (char*)Wl + s * 1024 + lane * 16);
  }

  // ---- issue-early prefetch of post-barrier globals (T14) ----
  // self: bias_t[nf][r]; mut: posW[u][r]. Shared register array, static idx.
  float pre_r[32];
  if (self) {
    const float* bt = bias_t + (size_t)h * 16384 + (m0 + lk * 4) * 128;
    #pragma unroll
    for (int nf = 0; nf < 8; ++nf)
      #pragma unroll
      for (int r = 0; r < 4; ++r)
        pre_r[nf * 4 + r] = bt[r * 128 + nf * 16 + lr];
  } else {
    #pragma unroll
    for (int u = 0; u < 6; ++u) {
      const int o = u >> 1, nt = u & 1;
      #pragma unroll
      for (int r = 0; r < 4; ++r)
        pre_r[u * 4 + r] = posW[(m0 + lk * 4 + r) * 768 + o * 256 + h * 32 + nt * 16 + lr];
    }
  }

  // ---- x: dist-2 register prefetch (rows m0..m0+15 disjoint per wave) ----
  const float*          xrowf = xf   + (size_t)((b * 128 + m0 + lr) * 256 + lk * 8);
  const unsigned short* xrowb = xb16 + (size_t)((b * 128 + m0 + lr) * 256 + lk * 8);

  float4 xrf[2][2];
  short8 xrb[2];
  if (XB) {
    xrb[0] = *(const short8*)(xrowb);
    xrb[1] = *(const short8*)(xrowb + 32);
  } else {
    xrf[0][0] = *(const float4*)(xrowf);
    xrf[0][1] = *(const float4*)(xrowf + 4);
    xrf[1][0] = *(const float4*)(xrowf + 32);
    xrf[1][1] = *(const float4*)(xrowf + 36);
  }

  __syncthreads();   // barrier 1: W staged (drains vmcnt incl. prefetches)

  // ======== Phase A: wave computes rows m0..m0+15 of [Q|K|V] (96 cols) ====
  f32x4 acc[6];
  #pragma unroll
  for (int u = 0; u < 6; ++u) acc[u] = f32x4{0.f, 0.f, 0.f, 0.f};

  const char* wfrag = (const char*)Wl + lane * 16;

  #pragma unroll
  for (int kc = 0; kc < 8; ++kc) {
    bf16x8 af;
    if (XB) {
      af = __builtin_bit_cast(bf16x8, xrb[kc & 1]);
      if (kc + 2 < 8) xrb[kc & 1] = *(const short8*)(xrowb + (kc + 2) * 32);
    } else {
      float4 a = xrf[kc & 1][0], d = xrf[kc & 1][1];
      if (kc + 2 < 8) {
        xrf[kc & 1][0] = *(const float4*)(xrowf + (kc + 2) * 32);
        xrf[kc & 1][1] = *(const float4*)(xrowf + (kc + 2) * 32 + 4);
      }
      af[0] = (__bf16)a.x; af[1] = (__bf16)a.y; af[2] = (__bf16)a.z; af[3] = (__bf16)a.w;
      af[4] = (__bf16)d.x; af[5] = (__bf16)d.y; af[6] = (__bf16)d.z; af[7] = (__bf16)d.w;
    }
    __builtin_amdgcn_s_setprio(1);
    #pragma unroll
    for (int u = 0; u < 6; ++u) {
      bf16x8 wf = *(const bf16x8*)(wfrag + ((u * 8 + kc) << 10));
      acc[u] = __builtin_amdgcn_mfma_f32_16x16x32_bf16(af, wf, acc[u], 0, 0, 0);
    }
    __builtin_amdgcn_s_setprio(0);
  }

  // epilogue: C layout row=(lane>>4)*4+r, col=lane&15
  #pragma unroll
  for (int u = 0; u < 6; ++u) {
    const int o = u >> 1, nt = u & 1;
    #pragma unroll
    for (int r = 0; r < 4; ++r) {
      int row  = m0 + lk * 4 + r;                  // token
      int dcol = nt * 16 + lr;                     // d within 32
      float v = acc[u][r];
      if (!self) v += pre_r[u * 4 + r];            // prefetched posW
      if (o == 2)      VT[dcol * 136 + row] = f2bf(v);
      else if (o == 0) Qsh[row * 40 + dcol] = f2bf(v);
      else             Ksh[row * 40 + dcol] = f2bf(v);
    }
  }
  __syncthreads();   // barrier 2: QKV visible; Wl dead -> Psh usable

  if (self) {
    // ======== self attention (128 keys, +bias; exp2, scale pre-folded) ========
    f32x4 sc[8];
    bf16x8 qa = *(const bf16x8*)&Qsh[(m0 + lr) * 40 + lk * 8];
    __builtin_amdgcn_s_setprio(1);
    #pragma unroll
    for (int nf = 0; nf < 8; ++nf) {
      bf16x8 kb = *(const bf16x8*)&Ksh[(nf * 16 + lr) * 40 + lk * 8];
      sc[nf] = __builtin_amdgcn_mfma_f32_16x16x32_bf16(qa, kb,
                                                       f32x4{0.f,0.f,0.f,0.f}, 0, 0, 0);
    }
    __builtin_amdgcn_s_setprio(0);
    float rsum[4] = {0.f, 0.f, 0.f, 0.f};
    #pragma unroll
    for (int nf = 0; nf < 8; ++nf)
      #pragma unroll
      for (int r = 0; r < 4; ++r) {
        float p = exp2f(sc[nf][r] + pre_r[nf * 4 + r]);   // prefetched bias
        rsum[r] += p;
        sc[nf][r] = p;
      }
    float rs[4];
    #pragma unroll
    for (int r = 0; r < 4; ++r) {
      float t = rsum[r];
      #pragma unroll
      for (int dd = 1; dd < 16; dd <<= 1) t += __shfl_xor(t, dd, 64);
      rs[r] = 1.f / t;
    }
    f32x4 oc[2];
    oc[0] = f32x4{0.f,0.f,0.f,0.f}; oc[1] = f32x4{0.f,0.f,0.f,0.f};
    #pragma unroll
    for (int c = 0; c < 4; ++c) {                  // 32-key chunks, P wave-private
      #pragma unroll
      for (int nf2 = 0; nf2 < 2; ++nf2)
        #pragma unroll
        for (int r = 0; r < 4; ++r)
          Psh[(m0 + lk * 4 + r) * 40 + nf2 * 16 + lr] = f2bf(sc[c * 2 + nf2][r]);
      bf16x8 pa = *(const bf16x8*)&Psh[(m0 + lr) * 40 + lk * 8];
      #pragma unroll
      for (int nt = 0; nt < 2; ++nt) {
        bf16x8 vb = *(const bf16x8*)&VT[(nt * 16 + lr) * 136 + c * 32 + lk * 8];
        oc[nt] = __builtin_amdgcn_mfma_f32_16x16x32_bf16(pa, vb, oc[nt], 0, 0, 0);
      }
    }
    #pragma unroll
    for (int nt = 0; nt < 2; ++nt)
      #pragma unroll
      for (int r = 0; r < 4; ++r) {
        size_t row = (size_t)b * 128 + m0 + lk * 4 + r;
        xcat[row * 512 + 256 + h * 32 + nt * 16 + lr] = f2bf(oc[nt][r] * rs[r]);
      }
  } else {
    // ======== mutual attention (half swap, 64 keys, no bias) ========
    const int q0   = (w < 4) ? 64 + m0 : m0 - 64;  // out rows 0..63 use q2; 64..127 q1
    const int koff = (w < 4) ? 0 : 64;             // k1/v1 vs k2/v2
    f32x4 sc2[4];
    bf16x8 qa = *(const bf16x8*)&Qsh[(q0 + lr) * 40 + lk * 8];
    __builtin_amdgcn_s_setprio(1);
    #pragma unroll
    for (int nf = 0; nf < 4; ++nf) {
      bf16x8 kb = *(const bf16x8*)&Ksh[(koff + nf * 16 + lr) * 40 + lk * 8];
      sc2[nf] = __builtin_amdgcn_mfma_f32_16x16x32_bf16(qa, kb,
                                                        f32x4{0.f,0.f,0.f,0.f}, 0, 0, 0);
    }
    __builtin_amdgcn_s_setprio(0);
    float rsum2[4] = {0.f, 0.f, 0.f, 0.f};
    #pragma unroll
    for (int nf = 0; nf < 4; ++nf)
      #pragma unroll
      for (int r = 0; r < 4; ++r) {
        float p = exp2f(sc2[nf][r]);
        rsum2[r] += p;
        sc2[nf][r] = p;
      }
    float rs2[4];
    #pragma unroll
    for (int r = 0; r < 4; ++r) {
      float t = rsum2[r];
      #pragma unroll
      for (int dd = 1; dd < 16; dd <<= 1) t += __shfl_xor(t, dd, 64);
      rs2[r] = 1.f / t;
    }
    f32x4 oc[2];
    oc[0] = f32x4{0.f,0.f,0.f,0.f}; oc[1] = f32x4{0.f,0.f,0.f,0.f};
    #pragma unroll
    for (int c = 0; c < 2; ++c) {
      #pragma unroll
      for (int nf2 = 0; nf2 < 2; ++nf2)
        #pragma unroll
        for (int r = 0; r < 4; ++r)
          Psh[(m0 + lk * 4 + r) * 40 + nf2 * 16 + lr] = f2bf(sc2[c * 2 + nf2][r]);
      bf16x8 pa = *(const bf16x8*)&Psh[(m0 + lr) * 40 + lk * 8];
      #pragma unroll
      for (int nt = 0; nt < 2; ++nt) {
        bf16x8 vb = *(const bf16x8*)&VT[(nt * 16 + lr) * 136 + koff + c * 32 + lk * 8];
        oc[nt] = __builtin_amdgcn_mfma_f32_16x16x32_bf16(pa, vb, oc[nt], 0, 0, 0);
      }
    }
    #pragma unroll
    for (int nt = 0; nt < 2; ++nt)
      #pragma unroll
      for (int r = 0; r < 4; ++r) {
        size_t row = (size_t)b * 128 + m0 + lk * 4 + r;
        xcat[row * 512 + h * 32 + nt * 16 + lr] = f2bf(oc[nt][r] * rs2[r]);
      }
  }
}

// ---------------- in-place projection GEMM (unchanged, proven) ----------------
// out[262144][256] f32 = xcat[262144][512] bf16 @ Wpb[256][512]^T + bp.
// xcat and out alias (d_out); row-tiles are block-exclusive.

__global__ __launch_bounds__(512, 2) void proj_kernel(
    const unsigned short* __restrict__ xcat,
    const unsigned short* __restrict__ Wpb,
    const float* __restrict__ bp,
    float* __restrict__ out)
{
  __shared__ unsigned short Alds[2][128 * 64];     // 2 x 16 KB
  __shared__ unsigned short Blds[2][256 * 64];     // 2 x 32 KB

  const int tid = threadIdx.x, w = tid >> 6, lane = tid & 63;
  const int lr = lane & 15, lk = lane >> 4;
  const int wr = w >> 2, wc = w & 3;               // 2 x 4 wave grid
  const size_t m0 = (size_t)blockIdx.x * 128;

  f32x4 acc[4][4];
  #pragma unroll
  for (int i = 0; i < 4; ++i)
    #pragma unroll
    for (int j = 0; j < 4; ++j) acc[i][j] = f32x4{0.f, 0.f, 0.f, 0.f};

  auto stage = [&](int buf, int k0) {
    #pragma unroll
    for (int i = 0; i < 2; ++i) {                  // A: 128 x 64 bf16
      int L = (i * 512 + tid) * 16;
      int row = L >> 7;
      int inrow = (L & 127) ^ ((row & 7) << 4);
      gload_lds16((const char*)xcat + (m0 + row) * 1024 + k0 * 2 + inrow,
                  (char*)&Alds[buf][0] + L);
    }
    #pragma unroll
    for (int i = 0; i < 4; ++i) {                  // B: 256 x 64 bf16
      int L = (i * 512 + tid) * 16;
      int row = L >> 7;
      int inrow = (L & 127) ^ ((row & 7) << 4);
      gload_lds16((const char*)Wpb + (size_t)row * 1024 + k0 * 2 + inrow,
                  (char*)&Blds[buf][0] + L);
    }
  };

  stage(0, 0);
  __syncthreads();
  int cur = 0;
  for (int t = 0; t < 8; ++t) {
    if (t < 7) stage(cur ^ 1, (t + 1) * 64);
    const char* At = (const char*)&Alds[cur][0];
    const char* Bt = (const char*)&Blds[cur][0];
    #pragma unroll
    for (int kk = 0; kk < 2; ++kk) {
      bf16x8 af[4], bfr[4];
      #pragma unroll
      for (int mt = 0; mt < 4; ++mt) {
        int row = wr * 64 + mt * 16 + lr;
        int off = (row * 128 + kk * 64 + lk * 16) ^ ((row & 7) << 4);
        af[mt] = *(const bf16x8*)(At + off);
      }
      #pragma unroll
      for (int nt = 0; nt < 4; ++nt) {
        int row = wc * 64 + nt * 16 + lr;
        int off = (row * 128 + kk * 64 + lk * 16) ^ ((row & 7) << 4);
        bfr[nt] = *(const bf16x8*)(Bt + off);
      }
      #pragma unroll
      for (int mt = 0; mt < 4; ++mt)
        #pragma unroll
        for (int nt = 0; nt < 4; ++nt)
          acc[mt][nt] = __builtin_amdgcn_mfma_f32_16x16x32_bf16(af[mt], bfr[nt],
                                                                acc[mt][nt], 0, 0, 0);
    }
    __syncthreads();
    cur ^= 1;
  }

  #pragma unroll
  for (int mt = 0; mt < 4; ++mt)
    #pragma unroll
    for (int r = 0; r < 4; ++r) {
      size_t grow = m0 + wr * 64 + mt * 16 + lk * 4 + r;
      #pragma unroll
      for (int nt = 0; nt < 4; ++nt) {
        int gcol = wc * 64 + nt * 16 + lr;
        out[grow * 256 + gcol] = acc[mt][nt][r] + bp[gcol];
      }
    }
}

// ---------------- launch ----------------

extern "C" void kernel_launch(void* const* d_in, const int* in_sizes, int n_in,
                              void* d_out, int out_size, void* d_ws, size_t ws_size,
                              hipStream_t stream) {
  (void)in_sizes; (void)n_in; (void)out_size;
  const float* x   = (const float*)d_in[0];
  const float* rpb = (const float*)d_in[1];
  const float* Wqs = (const float*)d_in[2];
  const float* Wqm = (const float*)d_in[3];
  const float* Wp  = (const float*)d_in[4];
  const float* bp  = (const float*)d_in[5];
  char* ws = (char*)d_ws;

  // workspace: tables (2,097,152 bytes) + optional xb16 (134,217,728 bytes)
  size_t off = 0;
  float* pos_t  = (float*)(ws + off); off += 32768ull  * 4;
  float* posW   = (float*)(ws + off); off += 98304ull  * 4;
  float* bias_t = (float*)(ws + off); off += 131072ull * 4;
  unsigned short* Wsb = (unsigned short*)(ws + off); off += 196608ull * 2;
  unsigned short* Wmb = (unsigned short*)(ws + off); off += 196608ull * 2;
  unsigned short* Wpb = (unsigned short*)(ws + off); off += 131072ull * 2;
  if (ws_size < off) return;                        // 2 MB — should always fit
  unsigned short* xb16 = (unsigned short*)(ws + off);
  const bool use_xb = (ws_size >= off + 67108864ull * 2);   // full x in bf16

  // xcat (bf16 [262144][512] = 268,435,456 B) lives in d_out; proj runs in-place.
  unsigned short* xcat = (unsigned short*)d_out;

  pos_kernel <<<dim3(128),  dim3(256), 0, stream>>>(pos_t);
  bias_kernel<<<dim3(512),  dim3(256), 0, stream>>>(rpb, bias_t);
  wconv_kernel<<<dim3(2048), dim3(256), 0, stream>>>(Wqs, Wqm, Wp, Wsb, Wmb, Wpb);
  posw_kernel<<<dim3(384),  dim3(256), 0, stream>>>(pos_t, Wqm, posW);

  if (use_xb) {
    xconv_kernel<<<dim3(8192), dim3(256), 0, stream>>>(x, xb16);
    qkv_attn<true><<<dim3(32768), dim3(512), 0, stream>>>(
        x, xb16, Wsb, Wmb, posW, bias_t, xcat);
  } else {
    qkv_attn<false><<<dim3(32768), dim3(512), 0, stream>>>(
        x, xb16, Wsb, Wmb, posW, bias_t, xcat);
  }

  proj_kernel<<<dim3(2048), dim3(512), 0, stream>>>(xcat, Wpb, bp, (float*)d_out);
}